// Round 4
// baseline (180.296 us; speedup 1.0000x reference)
//
#include <hip/hip_runtime.h>
#include <hip/hip_bf16.h>

// B=32, S=20 -> 640 graphs; N=128 nodes, F=64, HEADS=4, D=64.
#define ADJ_TH 0.05f

typedef __bf16 bf16x8 __attribute__((ext_vector_type(8)));
typedef __bf16 bf16x4 __attribute__((ext_vector_type(4)));
typedef float  f32x4  __attribute__((ext_vector_type(4)));

// ---- prep: block 0 transposes W -> Wt[256][64] bf16; block 1 builds
// WA[n][f] = sum_d W[f][h*64+d] * a[h][st*64+d], n = 2h+st (rows 8..15 zero) ----
__global__ __launch_bounds__(256)
void prep_kernel(const float* __restrict__ W, const float* __restrict__ a,
                 __bf16* __restrict__ Wt, __bf16* __restrict__ WAt) {
    const int t = threadIdx.x;
    if (blockIdx.x == 0) {
        #pragma unroll 4
        for (int r = 0; r < 64; ++r) {
            int id = r * 256 + t;                    // flat over W [64][256]
            Wt[(id & 255) * 64 + (id >> 8)] = (__bf16)W[id];
        }
    } else {
        for (int id = t; id < 1024; id += 256) {
            int n = id >> 6, f = id & 63;
            float s = 0.f;
            if (n < 8) {
                int hh = n >> 1, st = n & 1;
                #pragma unroll 8
                for (int d = 0; d < 64; ++d)
                    s += W[f * 256 + hh * 64 + d] * a[hh * 128 + st * 64 + d];
            }
            WAt[n * 64 + f] = (__bf16)s;
        }
    }
}

// Swizzled index into ht_t [128 rows (channel)][128 cols (node)] bf16.
__device__ __forceinline__ int sw_idx(int o, int i) {
    return o * 128 + ((((i >> 3) ^ o) & 15) << 3) + (i & 7);
}

__global__ __launch_bounds__(256, 3)
void gat_main_kernel(const float* __restrict__ hg, const float* __restrict__ adj,
                     const __bf16* __restrict__ Wt, const __bf16* __restrict__ WAt,
                     float* __restrict__ out)
{
    const int bs  = blockIdx.x;
    const int tid = threadIdx.x;
    const int w   = tid >> 6;
    const int l   = tid & 63;
    const int l15 = l & 15;
    const int l4  = l >> 4;

    __shared__ __bf16   ht_t[128 * 128];   // 32 KB
    __shared__ float    src_sh[4][128];    // 2 KB
    __shared__ float    tgt_sh[4][128];    // 2 KB
    __shared__ unsigned mask_sh[512];      // 2 KB

    const float* hb = hg  + (size_t)bs * 8192;
    const float* ab = adj + (size_t)bs * 16384;

    // ---- adjacency mask via ballot; wave w owns rows 32w..32w+31 ----
    // Per iter: 64 lanes read 64 consecutive floats (256B, coalesced), ballot
    // gives 64 mask bits = 2 words; lanes 0/1 store them.
    #pragma unroll 8
    for (int it = 0; it < 64; ++it) {
        int row = 32 * w + (it >> 1);
        int col = ((it & 1) << 6) + l;
        unsigned long long bal = __ballot(ab[row * 128 + col] < ADJ_TH);
        if (l < 2) mask_sh[row * 4 + ((it & 1) << 1) + l] = (unsigned)(bal >> (32 * l));
    }

    // ---- A fragments of h (held in 16 VGPRs) ----
    bf16x8 af[2][2];
    #pragma unroll
    for (int m2 = 0; m2 < 2; ++m2) {
        int row = 16 * (2 * w + m2) + l15;
        #pragma unroll
        for (int ks = 0; ks < 2; ++ks) {
            const float4* p4 = reinterpret_cast<const float4*>(hb + row * 64 + 8 * l4 + 32 * ks);
            float4 lo = p4[0], hi = p4[1];
            bf16x8 v;
            v[0]=(__bf16)lo.x; v[1]=(__bf16)lo.y; v[2]=(__bf16)lo.z; v[3]=(__bf16)lo.w;
            v[4]=(__bf16)hi.x; v[5]=(__bf16)hi.y; v[6]=(__bf16)hi.z; v[7]=(__bf16)hi.w;
            af[m2][ks] = v;
        }
    }

    // ---- src/tgt for ALL heads via 4 MFMAs: (h @ WA), C col n=2h+st ----
    {
        bf16x8 wa0 = *reinterpret_cast<const bf16x8*>(WAt + l15 * 64 + 8 * l4);
        bf16x8 wa1 = *reinterpret_cast<const bf16x8*>(WAt + l15 * 64 + 8 * l4 + 32);
        #pragma unroll
        for (int m2 = 0; m2 < 2; ++m2) {
            f32x4 acc = {0.f,0.f,0.f,0.f};
            acc = __builtin_amdgcn_mfma_f32_16x16x32_bf16(af[m2][0], wa0, acc, 0,0,0);
            acc = __builtin_amdgcn_mfma_f32_16x16x32_bf16(af[m2][1], wa1, acc, 0,0,0);
            if (l15 < 8) {
                int hh = l15 >> 1;
                float* dst = (l15 & 1) ? tgt_sh[hh] : src_sh[hh];
                int i0 = 16 * (2 * w + m2) + 4 * l4;
                #pragma unroll
                for (int r = 0; r < 4; ++r) dst[i0 + r] = acc[r];
            }
        }
    }
    __syncthreads();   // masks + src/tgt visible

    f32x4 acc2[2][4];
    #pragma unroll
    for (int m2 = 0; m2 < 2; ++m2)
        #pragma unroll
        for (int nt = 0; nt < 4; ++nt) { f32x4 z = {0.f,0.f,0.f,0.f}; acc2[m2][nt] = z; }

    // P-fragment builder for one head (pure VALU/trans; no barriers inside)
    auto compute_pa = [&](int hh, bf16x8 (&pa)[2][4]) {
        #pragma unroll
        for (int m2 = 0; m2 < 2; ++m2) {
            int irow = 16 * (2 * w + m2) + l15;
            float si = src_sh[hh][irow];
            uint4 mm = *reinterpret_cast<const uint4*>(&mask_sh[irow * 4]);
            unsigned mw[4] = {mm.x, mm.y, mm.z, mm.w};
            float pf[4][8];
            float dloc = 0.f;
            #pragma unroll
            for (int ks = 0; ks < 4; ++ks) {
                const float4* tp = reinterpret_cast<const float4*>(&tgt_sh[hh][8 * l4 + 32 * ks]);
                float4 t0 = tp[0], t1 = tp[1];
                float tg[8] = {t0.x,t0.y,t0.z,t0.w,t1.x,t1.y,t1.z,t1.w};
                #pragma unroll
                for (int e = 0; e < 8; ++e) {
                    float x  = si + tg[e];
                    float sg = __builtin_amdgcn_rcpf(1.0f + __expf(-x));
                    float pe = __expf(sg);
                    float pv = ((mw[ks] >> (8 * l4 + e)) & 1u) ? 0.f : pe;
                    pf[ks][e] = pv;
                    dloc += pv;
                }
            }
            dloc += __shfl_xor(dloc, 16);
            dloc += __shfl_xor(dloc, 32);
            float scale = 0.25f * __builtin_amdgcn_rcpf(fmaxf(dloc, 1e-20f));
            #pragma unroll
            for (int ks = 0; ks < 4; ++ks) {
                bf16x8 v;
                #pragma unroll
                for (int e = 0; e < 8; ++e) v[e] = (__bf16)(pf[ks][e] * scale);
                pa[m2][ks] = v;
            }
        }
    };

    auto gemm2 = [&](int hp, bf16x8 (&pa)[2][4]) {
        #pragma unroll
        for (int nt = 0; nt < 4; ++nt)
            #pragma unroll
            for (int ks = 0; ks < 4; ++ks) {
                bf16x8 b = *reinterpret_cast<const bf16x8*>(
                    &ht_t[sw_idx(64 * hp + 16 * nt + l15, 8 * l4 + 32 * ks)]);
                acc2[0][nt] = __builtin_amdgcn_mfma_f32_16x16x32_bf16(pa[0][ks], b, acc2[0][nt], 0,0,0);
                acc2[1][nt] = __builtin_amdgcn_mfma_f32_16x16x32_bf16(pa[1][ks], b, acc2[1][nt], 0,0,0);
            }
    };

    #pragma unroll 1
    for (int p = 0; p < 2; ++p) {          // pass = head pair {2p, 2p+1}
        // pa for head 2p first: its trans-pipe work interleaves with GEMM1 MFMA
        bf16x8 pa0[2][4];
        compute_pa(2 * p, pa0);

        // ---- GEMM1: 128 channels of this pass -> ht_t ----
        #pragma unroll
        for (int nt = 0; nt < 8; ++nt) {
            int oloc = 16 * nt + l15;
            const __bf16* wp = Wt + (size_t)(128 * p + oloc) * 64 + 8 * l4;
            bf16x8 b0 = *reinterpret_cast<const bf16x8*>(wp);
            bf16x8 b1 = *reinterpret_cast<const bf16x8*>(wp + 32);
            #pragma unroll
            for (int m2 = 0; m2 < 2; ++m2) {
                f32x4 acc = {0.f,0.f,0.f,0.f};
                acc = __builtin_amdgcn_mfma_f32_16x16x32_bf16(af[m2][0], b0, acc, 0,0,0);
                acc = __builtin_amdgcn_mfma_f32_16x16x32_bf16(af[m2][1], b1, acc, 0,0,0);
                int i0 = 16 * (2 * w + m2) + 4 * l4;
                bf16x4 st;
                st[0]=(__bf16)acc[0]; st[1]=(__bf16)acc[1];
                st[2]=(__bf16)acc[2]; st[3]=(__bf16)acc[3];
                *reinterpret_cast<bf16x4*>(&ht_t[sw_idx(oloc, i0)]) = st;
            }
        }
        __syncthreads();

        {
            // pa for head 2p+1 textually before GEMM2(2p): independent, interleaves
            bf16x8 pa1[2][4];
            compute_pa(2 * p + 1, pa1);
            gemm2(0, pa0);
            gemm2(1, pa1);
        }
        __syncthreads();   // ht_t reused next pass
    }

    // ---- epilogue ----
    float* ob = out + (size_t)bs * 8192;
    #pragma unroll
    for (int m2 = 0; m2 < 2; ++m2)
        #pragma unroll
        for (int nt = 0; nt < 4; ++nt)
            #pragma unroll
            for (int r = 0; r < 4; ++r)
                ob[(32 * w + 16 * m2 + 4 * l4 + r) * 64 + 16 * nt + l15] = acc2[m2][nt][r];
}

extern "C" void kernel_launch(void* const* d_in, const int* in_sizes, int n_in,
                              void* d_out, int out_size, void* d_ws, size_t ws_size,
                              hipStream_t stream) {
    const float* h   = (const float*)d_in[0];
    const float* adj = (const float*)d_in[1];
    const float* W   = (const float*)d_in[2];
    const float* a   = (const float*)d_in[3];
    float* out = (float*)d_out;

    __bf16* Wt  = (__bf16*)d_ws;                        // 32 KB
    __bf16* WAt = (__bf16*)((char*)d_ws + 32768);       // 2 KB

    prep_kernel<<<2, 256, 0, stream>>>(W, a, Wt, WAt);
    gat_main_kernel<<<640, 256, 0, stream>>>(h, adj, Wt, WAt, out);
}

// Round 5
// 165.630 us; speedup vs baseline: 1.0885x; 1.0885x over previous
//
#include <hip/hip_runtime.h>
#include <hip/hip_bf16.h>

// B=32, S=20 -> 640 graphs; N=128 nodes, F=64, HEADS=4, D=64.
#define ADJ_TH 0.05f

typedef __bf16 bf16x8 __attribute__((ext_vector_type(8)));
typedef __bf16 bf16x4 __attribute__((ext_vector_type(4)));
typedef float  f32x4  __attribute__((ext_vector_type(4)));

// ---- prep: block 0 transposes W -> Wt[256][64] bf16; block 1 builds
// WA[n][f] = sum_d W[f][h*64+d] * a[h][st*64+d], n = 2h+st (rows 8..15 zero) ----
__global__ __launch_bounds__(256)
void prep_kernel(const float* __restrict__ W, const float* __restrict__ a,
                 __bf16* __restrict__ Wt, __bf16* __restrict__ WAt) {
    const int t = threadIdx.x;
    if (blockIdx.x == 0) {
        #pragma unroll 4
        for (int r = 0; r < 64; ++r) {
            int id = r * 256 + t;                    // flat over W [64][256]
            Wt[(id & 255) * 64 + (id >> 8)] = (__bf16)W[id];
        }
    } else {
        for (int id = t; id < 1024; id += 256) {
            int n = id >> 6, f = id & 63;
            float s = 0.f;
            if (n < 8) {
                int hh = n >> 1, st = n & 1;
                #pragma unroll 8
                for (int d = 0; d < 64; ++d)
                    s += W[f * 256 + hh * 64 + d] * a[hh * 128 + st * 64 + d];
            }
            WAt[n * 64 + f] = (__bf16)s;
        }
    }
}

// Swizzled index into ht_t [128 rows (channel)][128 cols (node)] bf16.
__device__ __forceinline__ int sw_idx(int o, int i) {
    return o * 128 + ((((i >> 3) ^ o) & 15) << 3) + (i & 7);
}

__global__ __launch_bounds__(256, 3)
void gat_main_kernel(const float* __restrict__ hg, const float* __restrict__ adj,
                     const __bf16* __restrict__ Wt, const __bf16* __restrict__ WAt,
                     float* __restrict__ out)
{
    const int bs  = blockIdx.x;
    const int tid = threadIdx.x;
    const int w   = tid >> 6;
    const int l   = tid & 63;
    const int l15 = l & 15;
    const int l4  = l >> 4;

    __shared__ __bf16   ht_t[128 * 128];   // 32 KB
    __shared__ float    src_sh[4][128];    // 2 KB
    __shared__ float    tgt_sh[4][128];    // 2 KB
    __shared__ unsigned mask_sh[512];      // 2 KB

    const float* hb = hg  + (size_t)bs * 8192;
    const float* ab = adj + (size_t)bs * 16384;

    // ---- adjacency mask via ballot; wave w owns rows 32w..32w+31 ----
    // Per iter the wave reads 64 consecutive floats (256B, coalesced); ballot
    // yields 64 mask bits = 2 words; lanes 0/1 store them.
    #pragma unroll 8
    for (int it = 0; it < 64; ++it) {
        int row = 32 * w + (it >> 1);
        int col = ((it & 1) << 6) + l;
        unsigned long long bal = __ballot(ab[row * 128 + col] < ADJ_TH);
        if (l < 2) mask_sh[row * 4 + ((it & 1) << 1) + l] = (unsigned)(bal >> (32 * l));
    }

    // ---- A fragments of h (held in 16 VGPRs) ----
    bf16x8 af[2][2];
    #pragma unroll
    for (int m2 = 0; m2 < 2; ++m2) {
        int row = 16 * (2 * w + m2) + l15;
        #pragma unroll
        for (int ks = 0; ks < 2; ++ks) {
            const float4* p4 = reinterpret_cast<const float4*>(hb + row * 64 + 8 * l4 + 32 * ks);
            float4 lo = p4[0], hi = p4[1];
            bf16x8 v;
            v[0]=(__bf16)lo.x; v[1]=(__bf16)lo.y; v[2]=(__bf16)lo.z; v[3]=(__bf16)lo.w;
            v[4]=(__bf16)hi.x; v[5]=(__bf16)hi.y; v[6]=(__bf16)hi.z; v[7]=(__bf16)hi.w;
            af[m2][ks] = v;
        }
    }

    // ---- src/tgt for ALL heads via 4 MFMAs: (h @ WA); C col n=2h+st ----
    {
        bf16x8 wa0 = *reinterpret_cast<const bf16x8*>(WAt + l15 * 64 + 8 * l4);
        bf16x8 wa1 = *reinterpret_cast<const bf16x8*>(WAt + l15 * 64 + 8 * l4 + 32);
        #pragma unroll
        for (int m2 = 0; m2 < 2; ++m2) {
            f32x4 acc = {0.f,0.f,0.f,0.f};
            acc = __builtin_amdgcn_mfma_f32_16x16x32_bf16(af[m2][0], wa0, acc, 0,0,0);
            acc = __builtin_amdgcn_mfma_f32_16x16x32_bf16(af[m2][1], wa1, acc, 0,0,0);
            if (l15 < 8) {
                int hh = l15 >> 1;
                float* dst = (l15 & 1) ? tgt_sh[hh] : src_sh[hh];
                int i0 = 16 * (2 * w + m2) + 4 * l4;
                #pragma unroll
                for (int r = 0; r < 4; ++r) dst[i0 + r] = acc[r];
            }
        }
    }

    f32x4 acc2[2][4];
    #pragma unroll
    for (int m2 = 0; m2 < 2; ++m2)
        #pragma unroll
        for (int nt = 0; nt < 4; ++nt) { f32x4 z = {0.f,0.f,0.f,0.f}; acc2[m2][nt] = z; }

    #pragma unroll 1
    for (int p = 0; p < 2; ++p) {          // pass = head pair {2p, 2p+1}
        // ---- GEMM1: this pass's 128 channels -> ht_t (bf16, swizzled) ----
        #pragma unroll
        for (int nt = 0; nt < 8; ++nt) {
            int oloc = 16 * nt + l15;
            const __bf16* wp = Wt + (size_t)(128 * p + oloc) * 64 + 8 * l4;
            bf16x8 b0 = *reinterpret_cast<const bf16x8*>(wp);
            bf16x8 b1 = *reinterpret_cast<const bf16x8*>(wp + 32);
            #pragma unroll
            for (int m2 = 0; m2 < 2; ++m2) {
                f32x4 acc = {0.f,0.f,0.f,0.f};
                acc = __builtin_amdgcn_mfma_f32_16x16x32_bf16(af[m2][0], b0, acc, 0,0,0);
                acc = __builtin_amdgcn_mfma_f32_16x16x32_bf16(af[m2][1], b1, acc, 0,0,0);
                int i0 = 16 * (2 * w + m2) + 4 * l4;
                bf16x4 st;
                st[0]=(__bf16)acc[0]; st[1]=(__bf16)acc[1];
                st[2]=(__bf16)acc[2]; st[3]=(__bf16)acc[3];
                *reinterpret_cast<bf16x4*>(&ht_t[sw_idx(oloc, i0)]) = st;
            }
        }
        __syncthreads();   // ht_t (+ mask/src/tgt on p==0) visible

        // ---- phase 2: masked sigmoid-softmax + GEMM2, heads 2p, 2p+1 ----
        #pragma unroll 1
        for (int hp = 0; hp < 2; ++hp) {
            int hh = 2 * p + hp;
            // P fragments for both row-tiles (inline; consumed immediately)
            bf16x8 pa[2][4];
            #pragma unroll
            for (int m2 = 0; m2 < 2; ++m2) {
                int irow = 16 * (2 * w + m2) + l15;
                float si = src_sh[hh][irow];
                uint4 mm = *reinterpret_cast<const uint4*>(&mask_sh[irow * 4]);
                unsigned mw[4] = {mm.x, mm.y, mm.z, mm.w};
                float pf[4][8];
                float dloc = 0.f;
                #pragma unroll
                for (int ks = 0; ks < 4; ++ks) {
                    const float4* tp = reinterpret_cast<const float4*>(&tgt_sh[hh][8 * l4 + 32 * ks]);
                    float4 t0 = tp[0], t1 = tp[1];
                    float tg[8] = {t0.x,t0.y,t0.z,t0.w,t1.x,t1.y,t1.z,t1.w};
                    #pragma unroll
                    for (int e = 0; e < 8; ++e) {
                        float x  = si + tg[e];
                        float sg = __builtin_amdgcn_rcpf(1.0f + __expf(-x));
                        float pe = __expf(sg);
                        float pv = ((mw[ks] >> (8 * l4 + e)) & 1u) ? 0.f : pe;
                        pf[ks][e] = pv;
                        dloc += pv;
                    }
                }
                dloc += __shfl_xor(dloc, 16);
                dloc += __shfl_xor(dloc, 32);
                float scale = 0.25f * __builtin_amdgcn_rcpf(fmaxf(dloc, 1e-20f));
                #pragma unroll
                for (int ks = 0; ks < 4; ++ks) {
                    bf16x8 v;
                    #pragma unroll
                    for (int e = 0; e < 8; ++e) v[e] = (__bf16)(pf[ks][e] * scale);
                    pa[m2][ks] = v;
                }
            }

            // GEMM2: stream B fragments from LDS; each reused for both row-tiles
            #pragma unroll
            for (int nt = 0; nt < 4; ++nt)
                #pragma unroll
                for (int ks = 0; ks < 4; ++ks) {
                    bf16x8 b = *reinterpret_cast<const bf16x8*>(
                        &ht_t[sw_idx(64 * hp + 16 * nt + l15, 8 * l4 + 32 * ks)]);
                    acc2[0][nt] = __builtin_amdgcn_mfma_f32_16x16x32_bf16(pa[0][ks], b, acc2[0][nt], 0,0,0);
                    acc2[1][nt] = __builtin_amdgcn_mfma_f32_16x16x32_bf16(pa[1][ks], b, acc2[1][nt], 0,0,0);
                }
        }
        __syncthreads();   // ht_t reused next pass
    }

    // ---- epilogue ----
    float* ob = out + (size_t)bs * 8192;
    #pragma unroll
    for (int m2 = 0; m2 < 2; ++m2)
        #pragma unroll
        for (int nt = 0; nt < 4; ++nt)
            #pragma unroll
            for (int r = 0; r < 4; ++r)
                ob[(32 * w + 16 * m2 + 4 * l4 + r) * 64 + 16 * nt + l15] = acc2[m2][nt][r];
}

extern "C" void kernel_launch(void* const* d_in, const int* in_sizes, int n_in,
                              void* d_out, int out_size, void* d_ws, size_t ws_size,
                              hipStream_t stream) {
    const float* h   = (const float*)d_in[0];
    const float* adj = (const float*)d_in[1];
    const float* W   = (const float*)d_in[2];
    const float* a   = (const float*)d_in[3];
    float* out = (float*)d_out;

    __bf16* Wt  = (__bf16*)d_ws;                        // 32 KB
    __bf16* WAt = (__bf16*)((char*)d_ws + 32768);       // 2 KB

    prep_kernel<<<2, 256, 0, stream>>>(W, a, Wt, WAt);
    gat_main_kernel<<<640, 256, 0, stream>>>(h, adj, Wt, WAt, out);
}

// Round 6
// 138.251 us; speedup vs baseline: 1.3041x; 1.1980x over previous
//
#include <hip/hip_runtime.h>
#include <hip/hip_bf16.h>

// B=32, S=20 -> 640 graphs; N=128 nodes, F=64, HEADS=4, D=64.
#define ADJ_TH 0.05f

typedef __bf16 bf16x8 __attribute__((ext_vector_type(8)));
typedef __bf16 bf16x4 __attribute__((ext_vector_type(4)));
typedef float  f32x4  __attribute__((ext_vector_type(4)));

// ---- prep (73 blocks):
//   blocks 0..63 : transpose W [64][256] f32 -> Wt [256][64] bf16
//   blocks 64..71: WA row n = blk-64: WA[n][f] = sum_d W[f][hh*64+d]*a[hh][st*64+d]
//   block  72    : zero rows 8..15 of WAt
__global__ __launch_bounds__(256)
void prep_kernel(const float* __restrict__ W, const float* __restrict__ a,
                 __bf16* __restrict__ Wt, __bf16* __restrict__ WAt) {
    const int t = threadIdx.x, blk = blockIdx.x;
    if (blk < 64) {
        int id = blk * 256 + t;                  // flat over Wt [256][64]
        int o = id >> 6, k = id & 63;
        Wt[o * 64 + k] = (__bf16)W[k * 256 + o];
    } else if (blk < 72) {
        int n = blk - 64, hh = n >> 1, st = n & 1;
        int f = t >> 2, p = t & 3;
        const float* wp = W + f * 256 + hh * 64 + p * 16;
        const float* ap = a + hh * 128 + st * 64 + p * 16;
        float s = 0.f;
        #pragma unroll
        for (int d = 0; d < 16; ++d) s += wp[d] * ap[d];
        s += __shfl_xor(s, 1);
        s += __shfl_xor(s, 2);
        if (p == 0) WAt[n * 64 + f] = (__bf16)s;
    } else {
        WAt[512 + t] = (__bf16)0.f;
        WAt[768 + t] = (__bf16)0.f;
    }
}

// Swizzled index into ht_t [128 rows (channel)][128 cols (node)] bf16.
__device__ __forceinline__ int sw_idx(int o, int i) {
    return o * 128 + ((((i >> 3) ^ o) & 15) << 3) + (i & 7);
}

__global__ __launch_bounds__(256, 3)
void gat_main_kernel(const float* __restrict__ hg, const float* __restrict__ adj,
                     const __bf16* __restrict__ Wt, const __bf16* __restrict__ WAt,
                     float* __restrict__ out)
{
    const int bs  = blockIdx.x;
    const int tid = threadIdx.x;
    const int w   = tid >> 6;
    const int l   = tid & 63;
    const int l15 = l & 15;
    const int l4  = l >> 4;

    __shared__ __bf16   ht_t[128 * 128];   // 32 KB
    __shared__ float    src_sh[4][128];    // 2 KB
    __shared__ float    tgt_sh[4][128];    // 2 KB
    __shared__ unsigned mask_sh[512];      // 2 KB; [row][4]: col j -> word j&3, bit j>>2

    const float* hb = hg  + (size_t)bs * 8192;
    const float* ab = adj + (size_t)bs * 16384;

    // ---- (1) A fragments of h (issued first; 16 VGPRs held) ----
    bf16x8 af[2][2];
    #pragma unroll
    for (int m2 = 0; m2 < 2; ++m2) {
        int row = 16 * (2 * w + m2) + l15;
        #pragma unroll
        for (int ks = 0; ks < 2; ++ks) {
            const float4* p4 = reinterpret_cast<const float4*>(hb + row * 64 + 8 * l4 + 32 * ks);
            float4 lo = p4[0], hi = p4[1];
            bf16x8 v;
            v[0]=(__bf16)lo.x; v[1]=(__bf16)lo.y; v[2]=(__bf16)lo.z; v[3]=(__bf16)lo.w;
            v[4]=(__bf16)hi.x; v[5]=(__bf16)hi.y; v[6]=(__bf16)hi.z; v[7]=(__bf16)hi.w;
            af[m2][ks] = v;
        }
    }

    // ---- (2) src/tgt for ALL heads via 4 MFMAs: (h @ WA); C col n=2h+st ----
    {
        bf16x8 wa0 = *reinterpret_cast<const bf16x8*>(WAt + l15 * 64 + 8 * l4);
        bf16x8 wa1 = *reinterpret_cast<const bf16x8*>(WAt + l15 * 64 + 8 * l4 + 32);
        #pragma unroll
        for (int m2 = 0; m2 < 2; ++m2) {
            f32x4 acc = {0.f,0.f,0.f,0.f};
            acc = __builtin_amdgcn_mfma_f32_16x16x32_bf16(af[m2][0], wa0, acc, 0,0,0);
            acc = __builtin_amdgcn_mfma_f32_16x16x32_bf16(af[m2][1], wa1, acc, 0,0,0);
            if (l15 < 8) {
                int hh = l15 >> 1;
                float* dst = (l15 & 1) ? tgt_sh[hh] : src_sh[hh];
                int i0 = 16 * (2 * w + m2) + 4 * l4;
                #pragma unroll
                for (int r = 0; r < 4; ++r) dst[i0 + r] = acc[r];
            }
        }
    }

    // ---- GEMM1 for one pass (128 channels) -> ht_t ----
    auto gemm1 = [&](int p) {
        #pragma unroll
        for (int nt = 0; nt < 8; ++nt) {
            int oloc = 16 * nt + l15;
            const __bf16* wp = Wt + (size_t)(128 * p + oloc) * 64 + 8 * l4;
            bf16x8 b0 = *reinterpret_cast<const bf16x8*>(wp);
            bf16x8 b1 = *reinterpret_cast<const bf16x8*>(wp + 32);
            #pragma unroll
            for (int m2 = 0; m2 < 2; ++m2) {
                f32x4 acc = {0.f,0.f,0.f,0.f};
                acc = __builtin_amdgcn_mfma_f32_16x16x32_bf16(af[m2][0], b0, acc, 0,0,0);
                acc = __builtin_amdgcn_mfma_f32_16x16x32_bf16(af[m2][1], b1, acc, 0,0,0);
                int i0 = 16 * (2 * w + m2) + 4 * l4;
                bf16x4 st;
                st[0]=(__bf16)acc[0]; st[1]=(__bf16)acc[1];
                st[2]=(__bf16)acc[2]; st[3]=(__bf16)acc[3];
                *reinterpret_cast<bf16x4*>(&ht_t[sw_idx(oloc, i0)]) = st;
            }
        }
    };

    // ---- (3) GEMM1 pass 0 ----
    gemm1(0);

    // ---- (4) adjacency mask: float4 loads (1KB/wave/instr), 4 ballots each ----
    // Wave w, round rd covers rows {8rd+2w, 8rd+2w+1}.
    #pragma unroll 4
    for (int rd = 0; rd < 16; ++rd) {
        float4 f = *reinterpret_cast<const float4*>(ab + rd * 1024 + w * 256 + 4 * l);
        unsigned long long b0 = __ballot(f.x < ADJ_TH);
        unsigned long long b1 = __ballot(f.y < ADJ_TH);
        unsigned long long b2 = __ballot(f.z < ADJ_TH);
        unsigned long long b3 = __ballot(f.w < ADJ_TH);
        if (l < 2) {
            int row = 8 * rd + 2 * w + l;
            uint4 v;
            v.x = (unsigned)(b0 >> (32 * l));
            v.y = (unsigned)(b1 >> (32 * l));
            v.z = (unsigned)(b2 >> (32 * l));
            v.w = (unsigned)(b3 >> (32 * l));
            *reinterpret_cast<uint4*>(&mask_sh[row * 4]) = v;
        }
    }

    f32x4 acc2[2][4];
    #pragma unroll
    for (int m2 = 0; m2 < 2; ++m2)
        #pragma unroll
        for (int nt = 0; nt < 4; ++nt) { f32x4 z = {0.f,0.f,0.f,0.f}; acc2[m2][nt] = z; }

    // ---- phase 2 for one head-pair resident in ht_t ----
    auto phase2 = [&](int p) {
        #pragma unroll 1
        for (int hp = 0; hp < 2; ++hp) {
            int hh = 2 * p + hp;
            // tgt values for this lane's j-set (hoisted out of m2 loop)
            float tg[4][8];
            #pragma unroll
            for (int ks = 0; ks < 4; ++ks) {
                const float4* tp = reinterpret_cast<const float4*>(&tgt_sh[hh][8 * l4 + 32 * ks]);
                float4 t0 = tp[0], t1 = tp[1];
                tg[ks][0]=t0.x; tg[ks][1]=t0.y; tg[ks][2]=t0.z; tg[ks][3]=t0.w;
                tg[ks][4]=t1.x; tg[ks][5]=t1.y; tg[ks][6]=t1.z; tg[ks][7]=t1.w;
            }

            bf16x8 pa[2][4];
            #pragma unroll
            for (int m2 = 0; m2 < 2; ++m2) {
                int irow = 16 * (2 * w + m2) + l15;
                float si = src_sh[hh][irow];
                uint4 mm = *reinterpret_cast<const uint4*>(&mask_sh[irow * 4]);
                unsigned mw[4] = {mm.x, mm.y, mm.z, mm.w};
                float pf[4][8];
                float dloc = 0.f;
                #pragma unroll
                for (int ks = 0; ks < 4; ++ks) {
                    #pragma unroll
                    for (int e = 0; e < 8; ++e) {
                        float x  = si + tg[ks][e];
                        float sg = __builtin_amdgcn_rcpf(1.0f + __expf(-x));
                        float pe = __expf(sg);
                        // col j = 32ks + 8*l4 + e -> word e&3, bit 8ks + 2*l4 + (e>>2)
                        float pv = ((mw[e & 3] >> (8 * ks + 2 * l4 + (e >> 2))) & 1u) ? 0.f : pe;
                        pf[ks][e] = pv;
                        dloc += pv;
                    }
                }
                dloc += __shfl_xor(dloc, 16);
                dloc += __shfl_xor(dloc, 32);
                float scale = 0.25f * __builtin_amdgcn_rcpf(fmaxf(dloc, 1e-20f));
                #pragma unroll
                for (int ks = 0; ks < 4; ++ks) {
                    bf16x8 v;
                    #pragma unroll
                    for (int e = 0; e < 8; ++e) v[e] = (__bf16)(pf[ks][e] * scale);
                    pa[m2][ks] = v;
                }
            }

            // GEMM2: stream B fragments from LDS; each reused for both row-tiles
            #pragma unroll
            for (int nt = 0; nt < 4; ++nt)
                #pragma unroll
                for (int ks = 0; ks < 4; ++ks) {
                    bf16x8 b = *reinterpret_cast<const bf16x8*>(
                        &ht_t[sw_idx(64 * hp + 16 * nt + l15, 8 * l4 + 32 * ks)]);
                    acc2[0][nt] = __builtin_amdgcn_mfma_f32_16x16x32_bf16(pa[0][ks], b, acc2[0][nt], 0,0,0);
                    acc2[1][nt] = __builtin_amdgcn_mfma_f32_16x16x32_bf16(pa[1][ks], b, acc2[1][nt], 0,0,0);
                }
        }
    };

    // ---- (5..10) barrier-minimal 2-pass schedule ----
    __syncthreads();      // ht_t(p0) + mask + src/tgt visible
    phase2(0);
    __syncthreads();      // all reads of ht_t(p0) done
    gemm1(1);
    __syncthreads();      // ht_t(p1) visible
    phase2(1);

    // ---- epilogue ----
    float* ob = out + (size_t)bs * 8192;
    #pragma unroll
    for (int m2 = 0; m2 < 2; ++m2)
        #pragma unroll
        for (int nt = 0; nt < 4; ++nt)
            #pragma unroll
            for (int r = 0; r < 4; ++r)
                ob[(32 * w + 16 * m2 + 4 * l4 + r) * 64 + 16 * nt + l15] = acc2[m2][nt][r];
}

extern "C" void kernel_launch(void* const* d_in, const int* in_sizes, int n_in,
                              void* d_out, int out_size, void* d_ws, size_t ws_size,
                              hipStream_t stream) {
    const float* h   = (const float*)d_in[0];
    const float* adj = (const float*)d_in[1];
    const float* W   = (const float*)d_in[2];
    const float* a   = (const float*)d_in[3];
    float* out = (float*)d_out;

    __bf16* Wt  = (__bf16*)d_ws;                        // 32 KB
    __bf16* WAt = (__bf16*)((char*)d_ws + 32768);       // 2 KB

    prep_kernel<<<73, 256, 0, stream>>>(W, a, Wt, WAt);
    gat_main_kernel<<<640, 256, 0, stream>>>(h, adj, Wt, WAt, out);
}